// Round 9
// baseline (952.999 us; speedup 1.0000x reference)
//
#include <hip/hip_runtime.h>

typedef __bf16 bf16x8 __attribute__((ext_vector_type(8)));
typedef float  f32x4  __attribute__((ext_vector_type(4)));
typedef float  f32x16 __attribute__((ext_vector_type(16)));
typedef unsigned long long u64x2 __attribute__((ext_vector_type(2)));
typedef unsigned short u16;
typedef unsigned short us4 __attribute__((ext_vector_type(4)));

__device__ __forceinline__ u16 f2bf(float f) {
  __bf16 h = (__bf16)f;
  return __builtin_bit_cast(u16, h);
}

__device__ __forceinline__ void gload16(const void* g, void* l) {
  __builtin_amdgcn_global_load_lds(
      (const __attribute__((address_space(1))) unsigned int*)(g),
      (__attribute__((address_space(3))) unsigned int*)(l), 16, 0, 0);
}

__device__ __forceinline__ void barrier_lgkm() {
  asm volatile("s_waitcnt lgkmcnt(0)" ::: "memory");
  __builtin_amdgcn_s_barrier();
  asm volatile("" ::: "memory");
}
template <int N> __device__ __forceinline__ void vmwait() {
  asm volatile("s_waitcnt vmcnt(%0)" :: "n"(N) : "memory");
}

// ---------------- GroupNorm: pass 1 (partial sums) ----------------
__global__ void gn_partial(const float* __restrict__ x, float* __restrict__ part) {
  const int chunk = blockIdx.x, g = blockIdx.y, b = blockIdx.z;
  const int tid = threadIdx.x;
  float s = 0.f, ss = 0.f;
  const float* xb = x + ((size_t)(b * 4096 + chunk * 512)) * 512 + g * 16;
  for (int i = tid; i < 2048; i += 256) {
    const int sp = i >> 2, c4 = (i & 3) << 2;
    const float4 v = *(const float4*)(xb + (size_t)sp * 512 + c4);
    s  += v.x + v.y + v.z + v.w;
    ss += v.x * v.x + v.y * v.y + v.z * v.z + v.w * v.w;
  }
  for (int m = 32; m; m >>= 1) { s += __shfl_xor(s, m); ss += __shfl_xor(ss, m); }
  __shared__ float red[8];
  const int w = tid >> 6;
  if ((tid & 63) == 0) { red[w * 2] = s; red[w * 2 + 1] = ss; }
  __syncthreads();
  if (tid == 0) {
    float S = 0.f, SS = 0.f;
    for (int i = 0; i < 4; ++i) { S += red[2 * i]; SS += red[2 * i + 1]; }
    const int idx = ((b * 32 + g) * 8 + chunk) * 2;
    part[idx] = S; part[idx + 1] = SS;
  }
}

// ---------------- GroupNorm: pass 2 (finalize) ----------------
__global__ void gn_finalize(const float* __restrict__ part, float* __restrict__ stats) {
  const int t = threadIdx.x;  // 128 = 4*32
  if (t < 128) {
    float S = 0.f, SS = 0.f;
    for (int i = 0; i < 8; ++i) { S += part[(t * 8 + i) * 2]; SS += part[(t * 8 + i) * 2 + 1]; }
    const float mean = S * (1.0f / 65536.0f);
    const float var  = SS * (1.0f / 65536.0f) - mean * mean;
    stats[t * 2] = mean;
    stats[t * 2 + 1] = rsqrtf(var + 1e-6f);
  }
}

// ---------------- GroupNorm: pass 3 (normalize + cast bf16) ----------------
__global__ void gn_apply(const float* __restrict__ x, const float* __restrict__ gamma,
                         const float* __restrict__ beta, const float* __restrict__ stats,
                         u16* __restrict__ h) {
  const size_t i = (size_t)blockIdx.x * 256 + threadIdx.x;
  const size_t e = i * 4;
  const int c = (int)(e & 511);
  const int b = (int)(e >> 21);
  const int g = c >> 4;
  const float mean = stats[(b * 32 + g) * 2];
  const float rstd = stats[(b * 32 + g) * 2 + 1];
  const float4 xv = *(const float4*)(x + e);
  const float4 gv = *(const float4*)(gamma + c);
  const float4 bv = *(const float4*)(beta + c);
  us4 hv;
  hv.x = f2bf((xv.x - mean) * rstd * gv.x + bv.x);
  hv.y = f2bf((xv.y - mean) * rstd * gv.y + bv.y);
  hv.z = f2bf((xv.z - mean) * rstd * gv.z + bv.z);
  hv.w = f2bf((xv.w - mean) * rstd * gv.w + bv.w);
  *(us4*)(h + e) = hv;
}

// ---------------- fused weight transpose + cast (all 4 weights) ----------------
__global__ void wcast_t4(const float* __restrict__ wq, const float* __restrict__ wk,
                         const float* __restrict__ wv, const float* __restrict__ wo,
                         u16* __restrict__ wT) {
  const int idx = blockIdx.x * 256 + threadIdx.x;  // 0..1048575
  const int which = idx >> 18;
  const int rr = idx & 262143;
  const float* w = (which == 0) ? wq : (which == 1) ? wk : (which == 2) ? wv : wo;
  const int n = rr >> 9, k = rr & 511;
  wT[idx] = f2bf(w[k * 512 + n]);
}

#define GEMM_STAGE(buf, t)                                                       \
  {                                                                              \
    const int k0 = (t) * 32;                                                     \
    _Pragma("unroll")                                                            \
    for (int i = 0; i < 2; ++i) {                                                \
      const int cid = tid + i * 256;                                             \
      const int row = cid >> 2, cb = cid & 3;                                    \
      const int sc = (cb ^ (row & 3)) << 3;                                      \
      gload16(A + (size_t)(brow + row) * 512 + k0 + sc, &lA[buf][cid << 3]);     \
      gload16(Bt + (size_t)(bcol0 + row) * 512 + k0 + sc, &lB[buf][cid << 3]);   \
    }                                                                            \
  }

#define GEMM_MAIN                                                                \
  const f32x4 zero4 = {0.f, 0.f, 0.f, 0.f};                                      \
  f32x4 acc[4][4];                                                               \
  _Pragma("unroll") for (int a_ = 0; a_ < 4; ++a_)                               \
  _Pragma("unroll") for (int b_ = 0; b_ < 4; ++b_) acc[a_][b_] = zero4;          \
  GEMM_STAGE(0, 0);                                                              \
  asm volatile("s_waitcnt vmcnt(0)" ::: "memory");                               \
  __syncthreads();                                                               \
  int buf = 0;                                                                   \
  for (int t = 0; t < 16; ++t) {                                                 \
    if (t < 15) GEMM_STAGE(buf ^ 1, t + 1);                                      \
    bf16x8 af[4], bfv[4];                                                        \
    _Pragma("unroll") for (int f = 0; f < 4; ++f) {                              \
      const int ra = wr * 64 + f * 16 + l15;                                     \
      af[f] = *(const bf16x8*)(&lA[buf][(ra << 5) + ((lq ^ (ra & 3)) << 3)]);    \
      const int rb = wc * 64 + f * 16 + l15;                                     \
      bfv[f] = *(const bf16x8*)(&lB[buf][(rb << 5) + ((lq ^ (rb & 3)) << 3)]);   \
    }                                                                            \
    _Pragma("unroll") for (int fa = 0; fa < 4; ++fa)                             \
    _Pragma("unroll") for (int fb = 0; fb < 4; ++fb)                             \
      acc[fa][fb] = __builtin_amdgcn_mfma_f32_16x16x32_bf16(af[fa], bfv[fb],     \
                                                            acc[fa][fb], 0, 0, 0);\
    asm volatile("s_waitcnt vmcnt(0)" ::: "memory");                             \
    __syncthreads();                                                             \
    buf ^= 1;                                                                    \
  }

// ---------------- o-projection GEMM: f32 out, +bias +residual ----------------
__global__ __launch_bounds__(256)
void gemm_oproj(const u16* __restrict__ A, const u16* __restrict__ Bt,
                const float* __restrict__ bias, const float* __restrict__ resid,
                float* __restrict__ Cout) {
  const int tid = threadIdx.x;
  const int wid = tid >> 6, l = tid & 63;
  const int wr = wid >> 1, wc = wid & 1;
  const int l15 = l & 15, lq = l >> 4;
  const int brow = blockIdx.x * 128, bcol0 = blockIdx.y * 128;
  __shared__ u16 lA[2][4096];
  __shared__ u16 lB[2][4096];
  GEMM_MAIN
#pragma unroll
  for (int fa = 0; fa < 4; ++fa)
#pragma unroll
    for (int fb = 0; fb < 4; ++fb) {
      const int col = bcol0 + wc * 64 + fb * 16 + l15;
      const float bv = bias[col];
#pragma unroll
      for (int i = 0; i < 4; ++i) {
        const int row = brow + wr * 64 + fa * 16 + lq * 4 + i;
        const size_t idx = (size_t)row * 512 + col;
        Cout[idx] = acc[fa][fb][i] + bv + resid[idx];
      }
    }
}

// ---------------- fused QKV GEMM: grid (128, 12) ----------------
__global__ __launch_bounds__(256)
void gemm_qkv(const u16* __restrict__ A, const u16* __restrict__ wT,
              const float* __restrict__ bq, const float* __restrict__ bk,
              const float* __restrict__ bv_, u16* __restrict__ q,
              u16* __restrict__ k, u16* __restrict__ v8, float qs) {
  const int tid = threadIdx.x;
  const int wid = tid >> 6, l = tid & 63;
  const int wr = wid >> 1, wc = wid & 1;
  const int l15 = l & 15, lq = l >> 4;
  const int which = blockIdx.y >> 2;
  const int brow = blockIdx.x * 128, bcol0 = (blockIdx.y & 3) * 128;
  const u16* Bt = wT + which * 262144;
  const float* bias = (which == 0) ? bq : ((which == 1) ? bk : bv_);
  __shared__ u16 lA[2][4096];
  __shared__ u16 lB[2][4096];
  GEMM_MAIN
#pragma unroll
  for (int fa = 0; fa < 4; ++fa)
#pragma unroll
    for (int fb = 0; fb < 4; ++fb) {
      const int col = bcol0 + wc * 64 + fb * 16 + l15;
      const float bb_ = bias[col];
#pragma unroll
      for (int i = 0; i < 4; ++i) {
        const int row = brow + wr * 64 + fa * 16 + lq * 4 + i;
        const float v = acc[fa][fb][i] + bb_;
        if (which == 0) {
          q[(size_t)row * 512 + col] = f2bf(v * qs);
        } else if (which == 1) {
          k[(size_t)row * 512 + col] = f2bf(v);
        } else {
          const int bb = row >> 12, n = row & 4095;
          // V8 layout with chunk-XOR swizzle baked in (col ^= block&3)
          v8[((size_t)(bb * 512 + (n >> 3))) * 4096 +
             (size_t)((col ^ ((n >> 3) & 3)) << 3) + (n & 7)] = f2bf(v);
        }
      }
    }
}

// -------- flash attention v9: v8 structure + KV-split=2 (2 blocks/CU) --------
// grid 512: bid = qb*8 + z*4 + b  (bid%8 encodes (z,b) -> per-XCD working set
// = one batch's half-KV = 4 MB, L2-resident). Block = 384 threads:
//   wid 0,1  = S-waves; wid 2..5 = PV-waves (V direct-to-reg, K staging).
// Each block: 64 steps over its KV half; epilogue stores normalized partial O
// (bf16) + LSE; attn_combine merges the two halves.
__global__ __launch_bounds__(384, 3)
void attn_kernel(const u16* __restrict__ Q, const u16* __restrict__ K,
                 const u16* __restrict__ V8, u16* __restrict__ Op0,
                 u16* __restrict__ Op1, float* __restrict__ lsep) {
  const int bid = blockIdx.x;
  const int b = bid & 3, z = (bid >> 2) & 1, qb = bid >> 3;
  const int tid = threadIdx.x;
  const int wid = tid >> 6, l = tid & 63;
  const int l31 = l & 31, lh = l >> 5;

  // LDS: Kl[2] @0 (2x32768, [32][512] chunk^(row&15) swizzle); Pb[2] @65536
  // (2x4608, bf16 rows stride 72B); a[2] @74752 (2x256); flags @75264; lrow @75280
  __shared__ __align__(16) char lds[75536];
  const int PB = 65536, AB = 74752, FL = 75264, LR = 75280;

  const u16* Kb = K + (size_t)b * 2097152 + (size_t)z * 1048576;
  const u16* Vb = V8 + (size_t)b * 2097152 + (size_t)z * 1048576;

  const f32x16 z16 = {0.f,0.f,0.f,0.f, 0.f,0.f,0.f,0.f, 0.f,0.f,0.f,0.f, 0.f,0.f,0.f,0.f};

  if (wid < 2) {
    // =================== S-waves ===================
    const int qh = wid;
    bf16x8 qf[32];
    {
      const u16* qp = Q + ((size_t)(b * 4096 + qb * 64 + qh * 32 + l31)) * 512 + lh * 8;
#pragma unroll
      for (int kk = 0; kk < 32; ++kk) qf[kk] = *(const bf16x8*)(qp + kk * 16);
    }
    barrier_lgkm();                       // #0: K(0) staged by PV waves
    float m_ = -3e38f, l_ = 0.f;
    const int kxor = (l31 & 15) << 4;
    for (int t = 0; t < 64; ++t) {
      const char* kb = lds + ((t & 1) << 15) + l31 * 1024;
      f32x16 a0 = z16, a1 = z16, a2 = z16, a3 = z16;
#pragma unroll
      for (int kk = 0; kk < 32; kk += 4) {
        const bf16x8 k0 = *(const bf16x8*)(kb + ((kk * 32 + lh * 16) ^ kxor));
        a0 = __builtin_amdgcn_mfma_f32_32x32x16_bf16(k0, qf[kk], a0, 0, 0, 0);
        const bf16x8 k1 = *(const bf16x8*)(kb + (((kk + 1) * 32 + lh * 16) ^ kxor));
        a1 = __builtin_amdgcn_mfma_f32_32x32x16_bf16(k1, qf[kk + 1], a1, 0, 0, 0);
        const bf16x8 k2 = *(const bf16x8*)(kb + (((kk + 2) * 32 + lh * 16) ^ kxor));
        a2 = __builtin_amdgcn_mfma_f32_32x32x16_bf16(k2, qf[kk + 2], a2, 0, 0, 0);
        const bf16x8 k3 = *(const bf16x8*)(kb + (((kk + 3) * 32 + lh * 16) ^ kxor));
        a3 = __builtin_amdgcn_mfma_f32_32x32x16_bf16(k3, qf[kk + 3], a3, 0, 0, 0);
      }
      const f32x16 s = (a0 + a1) + (a2 + a3);
      // in-lane softmax: lane col = q, 16 kv here + 16 in lane^32
      float tmax = fmaxf(s[0], s[1]);
#pragma unroll
      for (int r2 = 2; r2 < 16; ++r2) tmax = fmaxf(tmax, s[r2]);
      tmax = fmaxf(tmax, __shfl_xor(tmax, 32));
      const bool need = tmax > m_ + 8.0f;
      const float mn = need ? tmax : m_;
      const float al = need ? __expf(m_ - mn) : 1.0f;
      float p[16];
#pragma unroll
      for (int r2 = 0; r2 < 16; ++r2) p[r2] = __expf(s[r2] - mn);
      float ps = 0.f;
#pragma unroll
      for (int r2 = 0; r2 < 16; ++r2) ps += p[r2];
      ps += __shfl_xor(ps, 32);
      l_ = l_ * al + ps;
      m_ = mn;
      // write P (kv-linear layout across rg/lh)
      char* prow = lds + PB + (t & 1) * 4608 + (qh * 32 + l31) * 72;
#pragma unroll
      for (int rg = 0; rg < 4; ++rg) {
        us4 pk4;
        pk4.x = f2bf(p[rg * 4 + 0]); pk4.y = f2bf(p[rg * 4 + 1]);
        pk4.z = f2bf(p[rg * 4 + 2]); pk4.w = f2bf(p[rg * 4 + 3]);
        *(unsigned long long*)(prow + rg * 16 + lh * 8) =
            __builtin_bit_cast(unsigned long long, pk4);
      }
      if (lh == 0) *(float*)(lds + AB + (t & 1) * 256 + (qh * 32 + l31) * 4) = al;
      const bool anyn = __any(need);
      if (l == 0) *(int*)(lds + FL + ((t & 1) * 2 + qh) * 4) = anyn ? 1 : 0;
      barrier_lgkm();
    }
    if (lh == 0) {
      *(float*)(lds + LR + (qh * 32 + l31) * 4) = l_;
      lsep[z * 16384 + b * 4096 + qb * 64 + qh * 32 + l31] = m_ + __logf(l_);
    }
    barrier_lgkm();                       // epilogue sync
  } else {
    // =================== PV-waves ===================
    const int dq = wid - 2;
    const int stid = (wid - 2) * 64 + l;  // 0..255 for K staging
    {
      char* kd = lds;
#pragma unroll
      for (int i = 0; i < 8; ++i) {
        const int cid = stid + i * 256;
        const int ob = cid << 4;
        const int n_ = ob >> 10;
        const int cb = (ob & 1023) ^ ((n_ & 15) << 4);
        gload16(Kb + (size_t)n_ * 512 + (cb >> 1), kd + ob);
      }
    }
    vmwait<0>();
    barrier_lgkm();                       // #0
    f32x16 o[2][4];
#pragma unroll
    for (int qt = 0; qt < 2; ++qt)
#pragma unroll
      for (int f = 0; f < 4; ++f) o[qt][f] = z16;
    bf16x8 vrA[8], vrB[8];

#define PV_APPLY(PB_, VUSE)                                                      \
    {                                                                            \
      bf16x8 pa[2][2];                                                           \
      _Pragma("unroll") for (int qt = 0; qt < 2; ++qt)                           \
      _Pragma("unroll") for (int h2 = 0; h2 < 2; ++h2) {                         \
        const char* pr = lds + PB + (PB_) * 4608 + (qt * 32 + l31) * 72 +        \
                         h2 * 32 + lh * 16;                                      \
        u64x2 w2;                                                                \
        w2[0] = *(const unsigned long long*)pr;                                  \
        w2[1] = *(const unsigned long long*)(pr + 8);                            \
        pa[qt][h2] = __builtin_bit_cast(bf16x8, w2);                             \
      }                                                                          \
      const int fl = *(const int*)(lds + FL + (PB_) * 8) |                       \
                     *(const int*)(lds + FL + (PB_) * 8 + 4);                    \
      if (fl) {                                                                  \
        _Pragma("unroll") for (int qt = 0; qt < 2; ++qt)                         \
        _Pragma("unroll") for (int rg = 0; rg < 16; ++rg) {                      \
          const int cr = (rg & 3) + 8 * (rg >> 2) + 4 * lh;                      \
          const float av = *(const float*)(lds + AB + (PB_) * 256 +              \
                                           (qt * 32 + cr) * 4);                  \
          _Pragma("unroll") for (int f = 0; f < 4; ++f) o[qt][f][rg] *= av;      \
        }                                                                        \
      }                                                                          \
      _Pragma("unroll") for (int f = 0; f < 4; ++f)                              \
      _Pragma("unroll") for (int h2 = 0; h2 < 2; ++h2) {                         \
        o[0][f] = __builtin_amdgcn_mfma_f32_32x32x16_bf16(pa[0][h2],             \
                      VUSE[f * 2 + h2], o[0][f], 0, 0, 0);                       \
        o[1][f] = __builtin_amdgcn_mfma_f32_32x32x16_bf16(pa[1][h2],             \
                      VUSE[f * 2 + h2], o[1][f], 0, 0, 0);                       \
      }                                                                          \
    }

#define PV_STEP(T, VUSE, VLOAD)                                                  \
    {                                                                            \
      const int t_ = (T);                                                        \
      if (t_ < 63) {                                                             \
        const u16* ks = Kb + (size_t)(t_ + 1) * 16384;                           \
        char* kd = lds + (((t_ + 1) & 1) << 15);                                 \
        _Pragma("unroll") for (int i = 0; i < 8; ++i) {                          \
          const int cid = stid + i * 256;                                        \
          const int ob = cid << 4;                                               \
          const int n_ = ob >> 10;                                               \
          const int cb = (ob & 1023) ^ ((n_ & 15) << 4);                         \
          gload16(ks + (size_t)n_ * 512 + (cb >> 1), kd + ob);                   \
        }                                                                        \
      }                                                                          \
      vmwait<8>();                        /* V(t-1) regs landed */               \
      if (t_ > 0) { PV_APPLY((t_ - 1) & 1, VUSE) }                               \
      {                                                                          \
        const u16* vsrc = Vb + (size_t)t_ * 16384;                               \
        _Pragma("unroll") for (int f = 0; f < 4; ++f)                            \
        _Pragma("unroll") for (int h2 = 0; h2 < 2; ++h2) {                       \
          const int c4 = h2 * 2 + lh;                                            \
          const int d = dq * 128 + f * 32 + l31;                                 \
          VLOAD[f * 2 + h2] =                                                    \
              *(const bf16x8*)(vsrc + ((size_t)(c4 * 512 + (d ^ c4)) << 3));     \
        }                                                                        \
      }                                                                          \
      vmwait<8>();                        /* K(t+1) landed, V(t) may fly */      \
      barrier_lgkm();                                                            \
    }

    for (int tt = 0; tt < 32; ++tt) {
      PV_STEP(2 * tt,     vrB, vrA)
      PV_STEP(2 * tt + 1, vrA, vrB)
    }
    vmwait<0>();                          // V(63) in vrB
    PV_APPLY(1, vrB)                      // P(63), a(63)
    barrier_lgkm();                       // lrow published
#undef PV_STEP
#undef PV_APPLY
    // epilogue: normalized partial O -> Op[z]
    u16* dstb = (z == 0 ? Op0 : Op1);
#pragma unroll
    for (int qt = 0; qt < 2; ++qt)
#pragma unroll
      for (int rg = 0; rg < 16; ++rg) {
        const int cr = (rg & 3) + 8 * (rg >> 2) + 4 * lh;
        const float li = 1.0f / *(const float*)(lds + LR + (qt * 32 + cr) * 4);
        u16* orow = dstb + ((size_t)(b * 4096 + qb * 64 + qt * 32 + cr)) * 512 + dq * 128 + l31;
#pragma unroll
        for (int f = 0; f < 4; ++f) orow[f * 32] = f2bf(o[qt][f][rg] * li);
      }
  }
}

// ---------------- combine the two KV-split partials (in place into O0) -------
__global__ void attn_combine(u16* __restrict__ O0, const u16* __restrict__ O1,
                             const float* __restrict__ lsep) {
  const int idx = blockIdx.x * 256 + threadIdx.x;  // 0..1048575
  const int row = idx >> 6;
  const int c8 = (idx & 63) << 3;
  const float e0 = lsep[row], e1 = lsep[16384 + row];
  const float M = fmaxf(e0, e1);
  float w0 = __expf(e0 - M), w1 = __expf(e1 - M);
  const float inv = 1.0f / (w0 + w1);
  w0 *= inv; w1 *= inv;
  const size_t base = (size_t)row * 512 + c8;
  const bf16x8 a = *(const bf16x8*)(O0 + base);
  const bf16x8 c = *(const bf16x8*)(O1 + base);
  bf16x8 rr;
#pragma unroll
  for (int j = 0; j < 8; ++j) rr[j] = (__bf16)(w0 * (float)a[j] + w1 * (float)c[j]);
  *(bf16x8*)(O0 + base) = rr;
}

extern "C" void kernel_launch(void* const* d_in, const int* in_sizes, int n_in,
                              void* d_out, int out_size, void* d_ws, size_t ws_size,
                              hipStream_t stream) {
  const float* x     = (const float*)d_in[0];
  const float* gamma = (const float*)d_in[1];
  const float* beta  = (const float*)d_in[2];
  const float* wq    = (const float*)d_in[3];
  const float* bq    = (const float*)d_in[4];
  const float* wk    = (const float*)d_in[5];
  const float* bk    = (const float*)d_in[6];
  const float* wv    = (const float*)d_in[7];
  const float* bv    = (const float*)d_in[8];
  const float* wo    = (const float*)d_in[9];
  const float* bo    = (const float*)d_in[10];
  float* out = (float*)d_out;

  char* ws = (char*)d_ws;
  const size_t SZ = (size_t)16384 * 512;
  u16* h    = (u16*)(ws);                 // 16 MB (Opart z=1 after gemm_qkv)
  u16* q    = (u16*)(ws + SZ * 2);        // 16 MB (pre-scaled by C^-0.5)
  u16* k    = (u16*)(ws + SZ * 4);        // 16 MB
  u16* v8   = (u16*)(ws + SZ * 6);        // 16 MB, [B][N/8][C^(blk&3)][8]
  u16* aout = (u16*)(ws + SZ * 8);        // 16 MB (Opart z=0, combined in place)
  u16* wT   = (u16*)(ws + SZ * 10);       // 4 x 512KB
  float* part  = (float*)(ws + SZ * 10 + 4 * 262144 * 2);
  float* stats = part + 2048;
  float* lse   = stats + 256;             // 2 x 16384 f32

  gn_partial<<<dim3(8, 32, 4), 256, 0, stream>>>(x, part);
  gn_finalize<<<1, 128, 0, stream>>>(part, stats);
  gn_apply<<<8192, 256, 0, stream>>>(x, gamma, beta, stats, h);

  wcast_t4<<<4096, 256, 0, stream>>>(wq, wk, wv, wo, wT);

  const float qs = 0.044194173824159216f;  // 512^-0.5
  gemm_qkv<<<dim3(128, 12), 256, 0, stream>>>(h, wT, bq, bk, bv, q, k, v8, qs);

  attn_kernel<<<512, 384, 0, stream>>>(q, k, v8, aout, h, lse);
  attn_combine<<<4096, 256, 0, stream>>>(aout, h, lse);

  gemm_oproj<<<dim3(128, 4), 256, 0, stream>>>(aout, wT + 3 * 262144, bo, x, out);
}

// Round 10
// 279.371 us; speedup vs baseline: 3.4112x; 3.4112x over previous
//
#include <hip/hip_runtime.h>

typedef __bf16 bf16x8 __attribute__((ext_vector_type(8)));
typedef float  f32x4  __attribute__((ext_vector_type(4)));
typedef float  f32x16 __attribute__((ext_vector_type(16)));
typedef unsigned long long u64x2 __attribute__((ext_vector_type(2)));
typedef unsigned short u16;
typedef unsigned short us4 __attribute__((ext_vector_type(4)));

__device__ __forceinline__ u16 f2bf(float f) {
  __bf16 h = (__bf16)f;
  return __builtin_bit_cast(u16, h);
}

__device__ __forceinline__ void gload16(const void* g, void* l) {
  __builtin_amdgcn_global_load_lds(
      (const __attribute__((address_space(1))) unsigned int*)(g),
      (__attribute__((address_space(3))) unsigned int*)(l), 16, 0, 0);
}

__device__ __forceinline__ void barrier_lgkm() {
  asm volatile("s_waitcnt lgkmcnt(0)" ::: "memory");
  __builtin_amdgcn_s_barrier();
  asm volatile("" ::: "memory");
}
template <int N> __device__ __forceinline__ void vmwait() {
  asm volatile("s_waitcnt vmcnt(%0)" :: "n"(N) : "memory");
}

// ---------------- GroupNorm: pass 1 (partial sums) ----------------
__global__ void gn_partial(const float* __restrict__ x, float* __restrict__ part) {
  const int chunk = blockIdx.x, g = blockIdx.y, b = blockIdx.z;
  const int tid = threadIdx.x;
  float s = 0.f, ss = 0.f;
  const float* xb = x + ((size_t)(b * 4096 + chunk * 512)) * 512 + g * 16;
  for (int i = tid; i < 2048; i += 256) {
    const int sp = i >> 2, c4 = (i & 3) << 2;
    const float4 v = *(const float4*)(xb + (size_t)sp * 512 + c4);
    s  += v.x + v.y + v.z + v.w;
    ss += v.x * v.x + v.y * v.y + v.z * v.z + v.w * v.w;
  }
  for (int m = 32; m; m >>= 1) { s += __shfl_xor(s, m); ss += __shfl_xor(ss, m); }
  __shared__ float red[8];
  const int w = tid >> 6;
  if ((tid & 63) == 0) { red[w * 2] = s; red[w * 2 + 1] = ss; }
  __syncthreads();
  if (tid == 0) {
    float S = 0.f, SS = 0.f;
    for (int i = 0; i < 4; ++i) { S += red[2 * i]; SS += red[2 * i + 1]; }
    const int idx = ((b * 32 + g) * 8 + chunk) * 2;
    part[idx] = S; part[idx + 1] = SS;
  }
}

// ---------------- GroupNorm: pass 2 (finalize) ----------------
__global__ void gn_finalize(const float* __restrict__ part, float* __restrict__ stats) {
  const int t = threadIdx.x;  // 128 = 4*32
  if (t < 128) {
    float S = 0.f, SS = 0.f;
    for (int i = 0; i < 8; ++i) { S += part[(t * 8 + i) * 2]; SS += part[(t * 8 + i) * 2 + 1]; }
    const float mean = S * (1.0f / 65536.0f);
    const float var  = SS * (1.0f / 65536.0f) - mean * mean;
    stats[t * 2] = mean;
    stats[t * 2 + 1] = rsqrtf(var + 1e-6f);
  }
}

// ---------------- GroupNorm: pass 3 (normalize + cast bf16) ----------------
__global__ void gn_apply(const float* __restrict__ x, const float* __restrict__ gamma,
                         const float* __restrict__ beta, const float* __restrict__ stats,
                         u16* __restrict__ h) {
  const size_t i = (size_t)blockIdx.x * 256 + threadIdx.x;
  const size_t e = i * 4;
  const int c = (int)(e & 511);
  const int b = (int)(e >> 21);
  const int g = c >> 4;
  const float mean = stats[(b * 32 + g) * 2];
  const float rstd = stats[(b * 32 + g) * 2 + 1];
  const float4 xv = *(const float4*)(x + e);
  const float4 gv = *(const float4*)(gamma + c);
  const float4 bv = *(const float4*)(beta + c);
  us4 hv;
  hv.x = f2bf((xv.x - mean) * rstd * gv.x + bv.x);
  hv.y = f2bf((xv.y - mean) * rstd * gv.y + bv.y);
  hv.z = f2bf((xv.z - mean) * rstd * gv.z + bv.z);
  hv.w = f2bf((xv.w - mean) * rstd * gv.w + bv.w);
  *(us4*)(h + e) = hv;
}

// ---------------- fused weight transpose + cast (all 4 weights) ----------------
__global__ void wcast_t4(const float* __restrict__ wq, const float* __restrict__ wk,
                         const float* __restrict__ wv, const float* __restrict__ wo,
                         u16* __restrict__ wT) {
  const int idx = blockIdx.x * 256 + threadIdx.x;  // 0..1048575
  const int which = idx >> 18;
  const int rr = idx & 262143;
  const float* w = (which == 0) ? wq : (which == 1) ? wk : (which == 2) ? wv : wo;
  const int n = rr >> 9, k = rr & 511;
  wT[idx] = f2bf(w[k * 512 + n]);
}

#define GEMM_STAGE(buf, t)                                                       \
  {                                                                              \
    const int k0 = (t) * 32;                                                     \
    _Pragma("unroll")                                                            \
    for (int i = 0; i < 2; ++i) {                                                \
      const int cid = tid + i * 256;                                             \
      const int row = cid >> 2, cb = cid & 3;                                    \
      const int sc = (cb ^ (row & 3)) << 3;                                      \
      gload16(A + (size_t)(brow + row) * 512 + k0 + sc, &lA[buf][cid << 3]);     \
      gload16(Bt + (size_t)(bcol0 + row) * 512 + k0 + sc, &lB[buf][cid << 3]);   \
    }                                                                            \
  }

#define GEMM_MAIN                                                                \
  const f32x4 zero4 = {0.f, 0.f, 0.f, 0.f};                                      \
  f32x4 acc[4][4];                                                               \
  _Pragma("unroll") for (int a_ = 0; a_ < 4; ++a_)                               \
  _Pragma("unroll") for (int b_ = 0; b_ < 4; ++b_) acc[a_][b_] = zero4;          \
  GEMM_STAGE(0, 0);                                                              \
  asm volatile("s_waitcnt vmcnt(0)" ::: "memory");                               \
  __syncthreads();                                                               \
  int buf = 0;                                                                   \
  for (int t = 0; t < 16; ++t) {                                                 \
    if (t < 15) GEMM_STAGE(buf ^ 1, t + 1);                                      \
    bf16x8 af[4], bfv[4];                                                        \
    _Pragma("unroll") for (int f = 0; f < 4; ++f) {                              \
      const int ra = wr * 64 + f * 16 + l15;                                     \
      af[f] = *(const bf16x8*)(&lA[buf][(ra << 5) + ((lq ^ (ra & 3)) << 3)]);    \
      const int rb = wc * 64 + f * 16 + l15;                                     \
      bfv[f] = *(const bf16x8*)(&lB[buf][(rb << 5) + ((lq ^ (rb & 3)) << 3)]);   \
    }                                                                            \
    _Pragma("unroll") for (int fa = 0; fa < 4; ++fa)                             \
    _Pragma("unroll") for (int fb = 0; fb < 4; ++fb)                             \
      acc[fa][fb] = __builtin_amdgcn_mfma_f32_16x16x32_bf16(af[fa], bfv[fb],     \
                                                            acc[fa][fb], 0, 0, 0);\
    asm volatile("s_waitcnt vmcnt(0)" ::: "memory");                             \
    __syncthreads();                                                             \
    buf ^= 1;                                                                    \
  }

// ---------------- o-projection GEMM: f32 out, +bias +residual ----------------
__global__ __launch_bounds__(256)
void gemm_oproj(const u16* __restrict__ A, const u16* __restrict__ Bt,
                const float* __restrict__ bias, const float* __restrict__ resid,
                float* __restrict__ Cout) {
  const int tid = threadIdx.x;
  const int wid = tid >> 6, l = tid & 63;
  const int wr = wid >> 1, wc = wid & 1;
  const int l15 = l & 15, lq = l >> 4;
  const int brow = blockIdx.x * 128, bcol0 = blockIdx.y * 128;
  __shared__ u16 lA[2][4096];
  __shared__ u16 lB[2][4096];
  GEMM_MAIN
#pragma unroll
  for (int fa = 0; fa < 4; ++fa)
#pragma unroll
    for (int fb = 0; fb < 4; ++fb) {
      const int col = bcol0 + wc * 64 + fb * 16 + l15;
      const float bv = bias[col];
#pragma unroll
      for (int i = 0; i < 4; ++i) {
        const int row = brow + wr * 64 + fa * 16 + lq * 4 + i;
        const size_t idx = (size_t)row * 512 + col;
        Cout[idx] = acc[fa][fb][i] + bv + resid[idx];
      }
    }
}

// ---------------- fused QKV GEMM: grid (128, 12) ----------------
__global__ __launch_bounds__(256)
void gemm_qkv(const u16* __restrict__ A, const u16* __restrict__ wT,
              const float* __restrict__ bq, const float* __restrict__ bk,
              const float* __restrict__ bv_, u16* __restrict__ q,
              u16* __restrict__ k, u16* __restrict__ v8, float qs) {
  const int tid = threadIdx.x;
  const int wid = tid >> 6, l = tid & 63;
  const int wr = wid >> 1, wc = wid & 1;
  const int l15 = l & 15, lq = l >> 4;
  const int which = blockIdx.y >> 2;
  const int brow = blockIdx.x * 128, bcol0 = (blockIdx.y & 3) * 128;
  const u16* Bt = wT + which * 262144;
  const float* bias = (which == 0) ? bq : ((which == 1) ? bk : bv_);
  __shared__ u16 lA[2][4096];
  __shared__ u16 lB[2][4096];
  GEMM_MAIN
#pragma unroll
  for (int fa = 0; fa < 4; ++fa)
#pragma unroll
    for (int fb = 0; fb < 4; ++fb) {
      const int col = bcol0 + wc * 64 + fb * 16 + l15;
      const float bb_ = bias[col];
#pragma unroll
      for (int i = 0; i < 4; ++i) {
        const int row = brow + wr * 64 + fa * 16 + lq * 4 + i;
        const float v = acc[fa][fb][i] + bb_;
        if (which == 0) {
          q[(size_t)row * 512 + col] = f2bf(v * qs);
        } else if (which == 1) {
          k[(size_t)row * 512 + col] = f2bf(v);
        } else {
          const int bb = row >> 12, n = row & 4095;
          // V8 layout with chunk-XOR swizzle baked in (col ^= block&3)
          v8[((size_t)(bb * 512 + (n >> 3))) * 4096 +
             (size_t)((col ^ ((n >> 3) & 3)) << 3) + (n & 7)] = f2bf(v);
        }
      }
    }
}

// -------- flash attention v10: v8 body + KV-split=2, NO register cap ---------
// grid 512: bid = qb*8 + z*4 + b. Block 384 threads; VGPR must stay ~128 so two
// blocks/CU co-schedule (128*3 waves/SIMD = 384 <= 512; LDS 2x75776 <= 160K).
__global__ __launch_bounds__(384)
void attn_kernel(const u16* __restrict__ Q, const u16* __restrict__ K,
                 const u16* __restrict__ V8, u16* __restrict__ Op0,
                 u16* __restrict__ Op1, float* __restrict__ lsep) {
  const int bid = blockIdx.x;
  const int b = bid & 3, z = (bid >> 2) & 1, qb = bid >> 3;
  const int tid = threadIdx.x;
  const int wid = tid >> 6, l = tid & 63;
  const int l31 = l & 31, lh = l >> 5;

  // LDS: Kl[2] @0 (2x32768, [32][512] chunk^(row&15) swizzle); Pb[2] @65536
  // (2x4608, bf16 rows stride 72B); a[2] @74752 (2x256); flags @75264; lrow @75280
  __shared__ __align__(16) char lds[75536];
  const int PB = 65536, AB = 74752, FL = 75264, LR = 75280;

  const u16* Kb = K + (size_t)b * 2097152 + (size_t)z * 1048576;
  const u16* Vb = V8 + (size_t)b * 2097152 + (size_t)z * 1048576;

  const f32x16 z16 = {0.f,0.f,0.f,0.f, 0.f,0.f,0.f,0.f, 0.f,0.f,0.f,0.f, 0.f,0.f,0.f,0.f};

  if (wid < 2) {
    // =================== S-waves ===================
    const int qh = wid;
    bf16x8 qf[32];
    {
      const u16* qp = Q + ((size_t)(b * 4096 + qb * 64 + qh * 32 + l31)) * 512 + lh * 8;
#pragma unroll
      for (int kk = 0; kk < 32; ++kk) qf[kk] = *(const bf16x8*)(qp + kk * 16);
    }
    barrier_lgkm();                       // #0: K(0) staged by PV waves
    float m_ = -3e38f, l_ = 0.f;
    const int kxor = (l31 & 15) << 4;
    for (int t = 0; t < 64; ++t) {
      const char* kb = lds + ((t & 1) << 15) + l31 * 1024;
      f32x16 a0 = z16, a1 = z16, a2 = z16, a3 = z16;
#pragma unroll
      for (int kk = 0; kk < 32; kk += 4) {
        const bf16x8 k0 = *(const bf16x8*)(kb + ((kk * 32 + lh * 16) ^ kxor));
        a0 = __builtin_amdgcn_mfma_f32_32x32x16_bf16(k0, qf[kk], a0, 0, 0, 0);
        const bf16x8 k1 = *(const bf16x8*)(kb + (((kk + 1) * 32 + lh * 16) ^ kxor));
        a1 = __builtin_amdgcn_mfma_f32_32x32x16_bf16(k1, qf[kk + 1], a1, 0, 0, 0);
        const bf16x8 k2 = *(const bf16x8*)(kb + (((kk + 2) * 32 + lh * 16) ^ kxor));
        a2 = __builtin_amdgcn_mfma_f32_32x32x16_bf16(k2, qf[kk + 2], a2, 0, 0, 0);
        const bf16x8 k3 = *(const bf16x8*)(kb + (((kk + 3) * 32 + lh * 16) ^ kxor));
        a3 = __builtin_amdgcn_mfma_f32_32x32x16_bf16(k3, qf[kk + 3], a3, 0, 0, 0);
      }
      const f32x16 s = (a0 + a1) + (a2 + a3);
      float tmax = fmaxf(s[0], s[1]);
#pragma unroll
      for (int r2 = 2; r2 < 16; ++r2) tmax = fmaxf(tmax, s[r2]);
      tmax = fmaxf(tmax, __shfl_xor(tmax, 32));
      const bool need = tmax > m_ + 8.0f;
      const float mn = need ? tmax : m_;
      const float al = need ? __expf(m_ - mn) : 1.0f;
      float p[16];
#pragma unroll
      for (int r2 = 0; r2 < 16; ++r2) p[r2] = __expf(s[r2] - mn);
      float ps = 0.f;
#pragma unroll
      for (int r2 = 0; r2 < 16; ++r2) ps += p[r2];
      ps += __shfl_xor(ps, 32);
      l_ = l_ * al + ps;
      m_ = mn;
      char* prow = lds + PB + (t & 1) * 4608 + (qh * 32 + l31) * 72;
#pragma unroll
      for (int rg = 0; rg < 4; ++rg) {
        us4 pk4;
        pk4.x = f2bf(p[rg * 4 + 0]); pk4.y = f2bf(p[rg * 4 + 1]);
        pk4.z = f2bf(p[rg * 4 + 2]); pk4.w = f2bf(p[rg * 4 + 3]);
        *(unsigned long long*)(prow + rg * 16 + lh * 8) =
            __builtin_bit_cast(unsigned long long, pk4);
      }
      if (lh == 0) *(float*)(lds + AB + (t & 1) * 256 + (qh * 32 + l31) * 4) = al;
      const bool anyn = __any(need);
      if (l == 0) *(int*)(lds + FL + ((t & 1) * 2 + qh) * 4) = anyn ? 1 : 0;
      barrier_lgkm();
    }
    if (lh == 0) {
      *(float*)(lds + LR + (qh * 32 + l31) * 4) = l_;
      lsep[z * 16384 + b * 4096 + qb * 64 + qh * 32 + l31] = m_ + __logf(l_);
    }
    barrier_lgkm();                       // epilogue sync
  } else {
    // =================== PV-waves ===================
    const int dq = wid - 2;
    const int stid = (wid - 2) * 64 + l;  // 0..255 for K staging
    {
      char* kd = lds;
#pragma unroll
      for (int i = 0; i < 8; ++i) {
        const int cid = stid + i * 256;
        const int ob = cid << 4;
        const int n_ = ob >> 10;
        const int cb = (ob & 1023) ^ ((n_ & 15) << 4);
        gload16(Kb + (size_t)n_ * 512 + (cb >> 1), kd + ob);
      }
    }
    vmwait<0>();
    barrier_lgkm();                       // #0
    f32x16 o[2][4];
#pragma unroll
    for (int qt = 0; qt < 2; ++qt)
#pragma unroll
      for (int f = 0; f < 4; ++f) o[qt][f] = z16;
    bf16x8 vrA[8], vrB[8];

#define PV_APPLY(PB_, VUSE)                                                      \
    {                                                                            \
      bf16x8 pa[2][2];                                                           \
      _Pragma("unroll") for (int qt = 0; qt < 2; ++qt)                           \
      _Pragma("unroll") for (int h2 = 0; h2 < 2; ++h2) {                         \
        const char* pr = lds + PB + (PB_) * 4608 + (qt * 32 + l31) * 72 +        \
                         h2 * 32 + lh * 16;                                      \
        u64x2 w2;                                                                \
        w2[0] = *(const unsigned long long*)pr;                                  \
        w2[1] = *(const unsigned long long*)(pr + 8);                            \
        pa[qt][h2] = __builtin_bit_cast(bf16x8, w2);                             \
      }                                                                          \
      const int fl = *(const int*)(lds + FL + (PB_) * 8) |                       \
                     *(const int*)(lds + FL + (PB_) * 8 + 4);                    \
      if (fl) {                                                                  \
        _Pragma("unroll") for (int qt = 0; qt < 2; ++qt)                         \
        _Pragma("unroll") for (int rg = 0; rg < 16; ++rg) {                      \
          const int cr = (rg & 3) + 8 * (rg >> 2) + 4 * lh;                      \
          const float av = *(const float*)(lds + AB + (PB_) * 256 +              \
                                           (qt * 32 + cr) * 4);                  \
          _Pragma("unroll") for (int f = 0; f < 4; ++f) o[qt][f][rg] *= av;      \
        }                                                                        \
      }                                                                          \
      _Pragma("unroll") for (int f = 0; f < 4; ++f)                              \
      _Pragma("unroll") for (int h2 = 0; h2 < 2; ++h2) {                         \
        o[0][f] = __builtin_amdgcn_mfma_f32_32x32x16_bf16(pa[0][h2],             \
                      VUSE[f * 2 + h2], o[0][f], 0, 0, 0);                       \
        o[1][f] = __builtin_amdgcn_mfma_f32_32x32x16_bf16(pa[1][h2],             \
                      VUSE[f * 2 + h2], o[1][f], 0, 0, 0);                       \
      }                                                                          \
    }

#define PV_STEP(T, VUSE, VLOAD)                                                  \
    {                                                                            \
      const int t_ = (T);                                                        \
      if (t_ < 63) {                                                             \
        const u16* ks = Kb + (size_t)(t_ + 1) * 16384;                           \
        char* kd = lds + (((t_ + 1) & 1) << 15);                                 \
        _Pragma("unroll") for (int i = 0; i < 8; ++i) {                          \
          const int cid = stid + i * 256;                                        \
          const int ob = cid << 4;                                               \
          const int n_ = ob >> 10;                                               \
          const int cb = (ob & 1023) ^ ((n_ & 15) << 4);                         \
          gload16(ks + (size_t)n_ * 512 + (cb >> 1), kd + ob);                   \
        }                                                                        \
      }                                                                          \
      vmwait<8>();                        /* V(t-1) regs landed */               \
      if (t_ > 0) { PV_APPLY((t_ - 1) & 1, VUSE) }                               \
      {                                                                          \
        const u16* vsrc = Vb + (size_t)t_ * 16384;                               \
        _Pragma("unroll") for (int f = 0; f < 4; ++f)                            \
        _Pragma("unroll") for (int h2 = 0; h2 < 2; ++h2) {                       \
          const int c4 = h2 * 2 + lh;                                            \
          const int d = dq * 128 + f * 32 + l31;                                 \
          VLOAD[f * 2 + h2] =                                                    \
              *(const bf16x8*)(vsrc + ((size_t)(c4 * 512 + (d ^ c4)) << 3));     \
        }                                                                        \
      }                                                                          \
      vmwait<8>();                        /* K(t+1) landed, V(t) may fly */      \
      barrier_lgkm();                                                            \
    }

    for (int tt = 0; tt < 32; ++tt) {
      PV_STEP(2 * tt,     vrB, vrA)
      PV_STEP(2 * tt + 1, vrA, vrB)
    }
    vmwait<0>();                          // V(63) in vrB
    PV_APPLY(1, vrB)                      // P(63), a(63)
    barrier_lgkm();                       // lrow published
#undef PV_STEP
#undef PV_APPLY
    // epilogue: normalized partial O -> Op[z]
    u16* dstb = (z == 0 ? Op0 : Op1);
#pragma unroll
    for (int qt = 0; qt < 2; ++qt)
#pragma unroll
      for (int rg = 0; rg < 16; ++rg) {
        const int cr = (rg & 3) + 8 * (rg >> 2) + 4 * lh;
        const float li = 1.0f / *(const float*)(lds + LR + (qt * 32 + cr) * 4);
        u16* orow = dstb + ((size_t)(b * 4096 + qb * 64 + qt * 32 + cr)) * 512 + dq * 128 + l31;
#pragma unroll
        for (int f = 0; f < 4; ++f) orow[f * 32] = f2bf(o[qt][f][rg] * li);
      }
  }
}

// ---------------- combine the two KV-split partials (in place into O0) -------
__global__ void attn_combine(u16* __restrict__ O0, const u16* __restrict__ O1,
                             const float* __restrict__ lsep) {
  const int idx = blockIdx.x * 256 + threadIdx.x;  // 0..1048575
  const int row = idx >> 6;
  const int c8 = (idx & 63) << 3;
  const float e0 = lsep[row], e1 = lsep[16384 + row];
  const float M = fmaxf(e0, e1);
  float w0 = __expf(e0 - M), w1 = __expf(e1 - M);
  const float inv = 1.0f / (w0 + w1);
  w0 *= inv; w1 *= inv;
  const size_t base = (size_t)row * 512 + c8;
  const bf16x8 a = *(const bf16x8*)(O0 + base);
  const bf16x8 c = *(const bf16x8*)(O1 + base);
  bf16x8 rr;
#pragma unroll
  for (int j = 0; j < 8; ++j) rr[j] = (__bf16)(w0 * (float)a[j] + w1 * (float)c[j]);
  *(bf16x8*)(O0 + base) = rr;
}

extern "C" void kernel_launch(void* const* d_in, const int* in_sizes, int n_in,
                              void* d_out, int out_size, void* d_ws, size_t ws_size,
                              hipStream_t stream) {
  const float* x     = (const float*)d_in[0];
  const float* gamma = (const float*)d_in[1];
  const float* beta  = (const float*)d_in[2];
  const float* wq    = (const float*)d_in[3];
  const float* bq    = (const float*)d_in[4];
  const float* wk    = (const float*)d_in[5];
  const float* bk    = (const float*)d_in[6];
  const float* wv    = (const float*)d_in[7];
  const float* bv    = (const float*)d_in[8];
  const float* wo    = (const float*)d_in[9];
  const float* bo    = (const float*)d_in[10];
  float* out = (float*)d_out;

  char* ws = (char*)d_ws;
  const size_t SZ = (size_t)16384 * 512;
  u16* h    = (u16*)(ws);                 // 16 MB (Opart z=1 after gemm_qkv)
  u16* q    = (u16*)(ws + SZ * 2);        // 16 MB (pre-scaled by C^-0.5)
  u16* k    = (u16*)(ws + SZ * 4);        // 16 MB
  u16* v8   = (u16*)(ws + SZ * 6);        // 16 MB, [B][N/8][C^(blk&3)][8]
  u16* aout = (u16*)(ws + SZ * 8);        // 16 MB (Opart z=0, combined in place)
  u16* wT   = (u16*)(ws + SZ * 10);       // 4 x 512KB
  float* part  = (float*)(ws + SZ * 10 + 4 * 262144 * 2);
  float* stats = part + 2048;
  float* lse   = stats + 256;             // 2 x 16384 f32

  gn_partial<<<dim3(8, 32, 4), 256, 0, stream>>>(x, part);
  gn_finalize<<<1, 128, 0, stream>>>(part, stats);
  gn_apply<<<8192, 256, 0, stream>>>(x, gamma, beta, stats, h);

  wcast_t4<<<4096, 256, 0, stream>>>(wq, wk, wv, wo, wT);

  const float qs = 0.044194173824159216f;  // 512^-0.5
  gemm_qkv<<<dim3(128, 12), 256, 0, stream>>>(h, wT, bq, bk, bv, q, k, v8, qs);

  attn_kernel<<<512, 384, 0, stream>>>(q, k, v8, aout, h, lse);
  attn_combine<<<4096, 256, 0, stream>>>(aout, h, lse);

  gemm_oproj<<<dim3(128, 4), 256, 0, stream>>>(aout, wT + 3 * 262144, bo, x, out);
}

// Round 12
// 249.967 us; speedup vs baseline: 3.8125x; 1.1176x over previous
//
#include <hip/hip_runtime.h>

typedef __bf16 bf16x8 __attribute__((ext_vector_type(8)));
typedef float  f32x4  __attribute__((ext_vector_type(4)));
typedef float  f32x16 __attribute__((ext_vector_type(16)));
typedef unsigned short u16;
typedef unsigned short us4 __attribute__((ext_vector_type(4)));

__device__ __forceinline__ u16 f2bf(float f) {
  __bf16 h = (__bf16)f;
  return __builtin_bit_cast(u16, h);
}

__device__ __forceinline__ void gload16(const void* g, void* l) {
  __builtin_amdgcn_global_load_lds(
      (const __attribute__((address_space(1))) unsigned int*)(g),
      (__attribute__((address_space(3))) unsigned int*)(l), 16, 0, 0);
}

__device__ __forceinline__ void barrier_lgkm() {
  asm volatile("s_waitcnt lgkmcnt(0)" ::: "memory");
  __builtin_amdgcn_s_barrier();
  asm volatile("" ::: "memory");
}
template <int N> __device__ __forceinline__ void vmwait() {
  asm volatile("s_waitcnt vmcnt(%0)" :: "n"(N) : "memory");
}

// ---------------- GroupNorm: pass 1 (partial sums) ----------------
__global__ void gn_partial(const float* __restrict__ x, float* __restrict__ part) {
  const int chunk = blockIdx.x, g = blockIdx.y, b = blockIdx.z;
  const int tid = threadIdx.x;
  float s = 0.f, ss = 0.f;
  const float* xb = x + ((size_t)(b * 4096 + chunk * 512)) * 512 + g * 16;
  for (int i = tid; i < 2048; i += 256) {
    const int sp = i >> 2, c4 = (i & 3) << 2;
    const float4 v = *(const float4*)(xb + (size_t)sp * 512 + c4);
    s  += v.x + v.y + v.z + v.w;
    ss += v.x * v.x + v.y * v.y + v.z * v.z + v.w * v.w;
  }
  for (int m = 32; m; m >>= 1) { s += __shfl_xor(s, m); ss += __shfl_xor(ss, m); }
  __shared__ float red[8];
  const int w = tid >> 6;
  if ((tid & 63) == 0) { red[w * 2] = s; red[w * 2 + 1] = ss; }
  __syncthreads();
  if (tid == 0) {
    float S = 0.f, SS = 0.f;
    for (int i = 0; i < 4; ++i) { S += red[2 * i]; SS += red[2 * i + 1]; }
    const int idx = ((b * 32 + g) * 8 + chunk) * 2;
    part[idx] = S; part[idx + 1] = SS;
  }
}

// ---------------- GroupNorm: pass 2 (finalize) ----------------
__global__ void gn_finalize(const float* __restrict__ part, float* __restrict__ stats) {
  const int t = threadIdx.x;  // 128 = 4*32
  if (t < 128) {
    float S = 0.f, SS = 0.f;
    for (int i = 0; i < 8; ++i) { S += part[(t * 8 + i) * 2]; SS += part[(t * 8 + i) * 2 + 1]; }
    const float mean = S * (1.0f / 65536.0f);
    const float var  = SS * (1.0f / 65536.0f) - mean * mean;
    stats[t * 2] = mean;
    stats[t * 2 + 1] = rsqrtf(var + 1e-6f);
  }
}

// ---------------- GroupNorm: pass 3 (normalize + cast bf16) ----------------
__global__ void gn_apply(const float* __restrict__ x, const float* __restrict__ gamma,
                         const float* __restrict__ beta, const float* __restrict__ stats,
                         u16* __restrict__ h) {
  const size_t i = (size_t)blockIdx.x * 256 + threadIdx.x;
  const size_t e = i * 4;
  const int c = (int)(e & 511);
  const int b = (int)(e >> 21);
  const int g = c >> 4;
  const float mean = stats[(b * 32 + g) * 2];
  const float rstd = stats[(b * 32 + g) * 2 + 1];
  const float4 xv = *(const float4*)(x + e);
  const float4 gv = *(const float4*)(gamma + c);
  const float4 bv = *(const float4*)(beta + c);
  us4 hv;
  hv.x = f2bf((xv.x - mean) * rstd * gv.x + bv.x);
  hv.y = f2bf((xv.y - mean) * rstd * gv.y + bv.y);
  hv.z = f2bf((xv.z - mean) * rstd * gv.z + bv.z);
  hv.w = f2bf((xv.w - mean) * rstd * gv.w + bv.w);
  *(us4*)(h + e) = hv;
}

// ---------------- fused weight transpose + cast (all 4 weights) ----------------
__global__ void wcast_t4(const float* __restrict__ wq, const float* __restrict__ wk,
                         const float* __restrict__ wv, const float* __restrict__ wo,
                         u16* __restrict__ wT) {
  const int idx = blockIdx.x * 256 + threadIdx.x;  // 0..1048575
  const int which = idx >> 18;
  const int rr = idx & 262143;
  const float* w = (which == 0) ? wq : (which == 1) ? wk : (which == 2) ? wv : wo;
  const int n = rr >> 9, k = rr & 511;
  wT[idx] = f2bf(w[k * 512 + n]);
}

#define GEMM_STAGE(buf, t)                                                       \
  {                                                                              \
    const int k0 = (t) * 32;                                                     \
    _Pragma("unroll")                                                            \
    for (int i = 0; i < 2; ++i) {                                                \
      const int cid = tid + i * 256;                                             \
      const int row = cid >> 2, cb = cid & 3;                                    \
      const int sc = (cb ^ (row & 3)) << 3;                                      \
      gload16(A + (size_t)(brow + row) * 512 + k0 + sc, &lA[buf][cid << 3]);     \
      gload16(Bt + (size_t)(bcol0 + row) * 512 + k0 + sc, &lB[buf][cid << 3]);   \
    }                                                                            \
  }

#define GEMM_MAIN                                                                \
  const f32x4 zero4 = {0.f, 0.f, 0.f, 0.f};                                      \
  f32x4 acc[4][4];                                                               \
  _Pragma("unroll") for (int a_ = 0; a_ < 4; ++a_)                               \
  _Pragma("unroll") for (int b_ = 0; b_ < 4; ++b_) acc[a_][b_] = zero4;          \
  GEMM_STAGE(0, 0);                                                              \
  asm volatile("s_waitcnt vmcnt(0)" ::: "memory");                               \
  __syncthreads();                                                               \
  int buf = 0;                                                                   \
  for (int t = 0; t < 16; ++t) {                                                 \
    if (t < 15) GEMM_STAGE(buf ^ 1, t + 1);                                      \
    bf16x8 af[4], bfv[4];                                                        \
    _Pragma("unroll") for (int f = 0; f < 4; ++f) {                              \
      const int ra = wr * 64 + f * 16 + l15;                                     \
      af[f] = *(const bf16x8*)(&lA[buf][(ra << 5) + ((lq ^ (ra & 3)) << 3)]);    \
      const int rb = wc * 64 + f * 16 + l15;                                     \
      bfv[f] = *(const bf16x8*)(&lB[buf][(rb << 5) + ((lq ^ (rb & 3)) << 3)]);   \
    }                                                                            \
    _Pragma("unroll") for (int fa = 0; fa < 4; ++fa)                             \
    _Pragma("unroll") for (int fb = 0; fb < 4; ++fb)                             \
      acc[fa][fb] = __builtin_amdgcn_mfma_f32_16x16x32_bf16(af[fa], bfv[fb],     \
                                                            acc[fa][fb], 0, 0, 0);\
    asm volatile("s_waitcnt vmcnt(0)" ::: "memory");                             \
    __syncthreads();                                                             \
    buf ^= 1;                                                                    \
  }

// ---------------- o-projection GEMM: f32 out, +bias +residual ----------------
__global__ __launch_bounds__(256)
void gemm_oproj(const u16* __restrict__ A, const u16* __restrict__ Bt,
                const float* __restrict__ bias, const float* __restrict__ resid,
                float* __restrict__ Cout) {
  const int tid = threadIdx.x;
  const int wid = tid >> 6, l = tid & 63;
  const int wr = wid >> 1, wc = wid & 1;
  const int l15 = l & 15, lq = l >> 4;
  const int brow = blockIdx.x * 128, bcol0 = blockIdx.y * 128;
  __shared__ u16 lA[2][4096];
  __shared__ u16 lB[2][4096];
  GEMM_MAIN
#pragma unroll
  for (int fa = 0; fa < 4; ++fa)
#pragma unroll
    for (int fb = 0; fb < 4; ++fb) {
      const int col = bcol0 + wc * 64 + fb * 16 + l15;
      const float bv = bias[col];
#pragma unroll
      for (int i = 0; i < 4; ++i) {
        const int row = brow + wr * 64 + fa * 16 + lq * 4 + i;
        const size_t idx = (size_t)row * 512 + col;
        Cout[idx] = acc[fa][fb][i] + bv + resid[idx];
      }
    }
}

// ---------------- fused QKV GEMM: grid (128, 12) ----------------
__global__ __launch_bounds__(256)
void gemm_qkv(const u16* __restrict__ A, const u16* __restrict__ wT,
              const float* __restrict__ bq, const float* __restrict__ bk,
              const float* __restrict__ bv_, u16* __restrict__ q,
              u16* __restrict__ k, u16* __restrict__ v8, float qs) {
  const int tid = threadIdx.x;
  const int wid = tid >> 6, l = tid & 63;
  const int wr = wid >> 1, wc = wid & 1;
  const int l15 = l & 15, lq = l >> 4;
  const int which = blockIdx.y >> 2;
  const int brow = blockIdx.x * 128, bcol0 = (blockIdx.y & 3) * 128;
  const u16* Bt = wT + which * 262144;
  const float* bias = (which == 0) ? bq : ((which == 1) ? bk : bv_);
  __shared__ u16 lA[2][4096];
  __shared__ u16 lB[2][4096];
  GEMM_MAIN
#pragma unroll
  for (int fa = 0; fa < 4; ++fa)
#pragma unroll
    for (int fb = 0; fb < 4; ++fb) {
      const int col = bcol0 + wc * 64 + fb * 16 + l15;
      const float bb_ = bias[col];
#pragma unroll
      for (int i = 0; i < 4; ++i) {
        const int row = brow + wr * 64 + fa * 16 + lq * 4 + i;
        const float v = acc[fa][fb][i] + bb_;
        if (which == 0) {
          q[(size_t)row * 512 + col] = f2bf(v * qs);
        } else if (which == 1) {
          k[(size_t)row * 512 + col] = f2bf(v);
        } else {
          const int bb = row >> 12, n = row & 4095;
          // V8 layout with chunk-XOR swizzle baked in (col ^= block&3)
          v8[((size_t)(bb * 512 + (n >> 3))) * 4096 +
             (size_t)((col ^ ((n >> 3) & 3)) << 3) + (n & 7)] = f2bf(v);
        }
      }
    }
}

// ------ flash attention v12: 12 thin waves (3/SIMD), FULL 128-step KV loop ----
// grid 256 (b = bid&3 -> XCD), block 768:
//   wid 0..3  = S-waves (w): S^T[32kv][16q] via 16x16x32 mfma(K,Q), in-lane
//               softmax, write P bf16 + a + flag.
//   wid 4..11 = PV-waves (pw): O[64q][64d] += P(t-1) V(t-1) (32x32x16);
//               V direct-to-reg; K(t+2) staged via global_load_lds (3 bufs).
// One barrier/step; counted vmcnt (never waits on same-step loads).
__global__ __launch_bounds__(768, 3)
void attn_kernel(const u16* __restrict__ Q, const u16* __restrict__ K,
                 const u16* __restrict__ V8, u16* __restrict__ Oo) {
  const int bid = blockIdx.x;
  const int b = bid & 3, qb = bid >> 2;
  const int tid = threadIdx.x;
  const int wid = tid >> 6, l = tid & 63;
  const int l31 = l & 31, lh = l >> 5;
  const int l15 = l & 15, lq = l >> 4;

  // LDS: K 3x32768 @0 ([32][512] bf16, chunk^(row&15)); P 2x4608 @98304
  // (bf16 [64 q][72B], kv-linear); a 2x256 @107520; flags 2x16 @108032; lrow @108064
  __shared__ __align__(16) char lds[108320];
  const int PB = 98304, AB = 107520, FL = 108032, LR = 108064;

  const u16* Kb = K + (size_t)b * 2097152;
  const u16* Vb = V8 + (size_t)b * 2097152;

  const f32x4 z4 = {0.f, 0.f, 0.f, 0.f};

  if (wid < 4) {
    // =================== S-waves ===================
    const int w = wid;
    bf16x8 qf[16];
    {
      const u16* qp = Q + ((size_t)(b * 4096 + qb * 64 + w * 16 + l15)) * 512 + lq * 8;
#pragma unroll
      for (int kk = 0; kk < 16; ++kk) qf[kk] = *(const bf16x8*)(qp + kk * 32);
    }
    barrier_lgkm();                       // #0: K(0) staged
    float m_ = -3e38f, l_ = 0.f;
    const int swz = l15 << 4;
    for (int t = 0; t < 128; ++t) {
      const char* kb = lds + (t % 3) * 32768;
      const char* r0 = kb + l15 * 1024;          // kv rows 0..15
      const char* r1 = kb + (16 + l15) * 1024;   // kv rows 16..31
      f32x4 a0 = z4, a1 = z4, a2 = z4, a3 = z4;
#pragma unroll
      for (int kk = 0; kk < 16; kk += 2) {
        const int o0 = (kk * 64 + lq * 16) ^ swz;
        const int o1 = ((kk + 1) * 64 + lq * 16) ^ swz;
        a0 = __builtin_amdgcn_mfma_f32_16x16x32_bf16(*(const bf16x8*)(r0 + o0), qf[kk], a0, 0, 0, 0);
        a1 = __builtin_amdgcn_mfma_f32_16x16x32_bf16(*(const bf16x8*)(r1 + o0), qf[kk], a1, 0, 0, 0);
        a2 = __builtin_amdgcn_mfma_f32_16x16x32_bf16(*(const bf16x8*)(r0 + o1), qf[kk + 1], a2, 0, 0, 0);
        a3 = __builtin_amdgcn_mfma_f32_16x16x32_bf16(*(const bf16x8*)(r1 + o1), qf[kk + 1], a3, 0, 0, 0);
      }
      const f32x4 s0 = a0 + a2;   // kv = lq*4+i
      const f32x4 s1 = a1 + a3;   // kv = 16 + lq*4+i
      float tmax = fmaxf(fmaxf(fmaxf(s0[0], s0[1]), fmaxf(s0[2], s0[3])),
                         fmaxf(fmaxf(s1[0], s1[1]), fmaxf(s1[2], s1[3])));
      tmax = fmaxf(tmax, __shfl_xor(tmax, 16));
      tmax = fmaxf(tmax, __shfl_xor(tmax, 32));
      const bool need = tmax > m_ + 8.0f;
      const float mn = need ? tmax : m_;
      const float al = need ? __expf(m_ - mn) : 1.0f;
      float p0[4], p1[4];
#pragma unroll
      for (int i = 0; i < 4; ++i) { p0[i] = __expf(s0[i] - mn); p1[i] = __expf(s1[i] - mn); }
      float ps = (p0[0] + p0[1]) + (p0[2] + p0[3]) + (p1[0] + p1[1]) + (p1[2] + p1[3]);
      ps += __shfl_xor(ps, 16);
      ps += __shfl_xor(ps, 32);
      l_ = l_ * al + ps;
      m_ = mn;
      // write P (kv-linear: byte = kv*2), rows stride 72B
      char* prow = lds + PB + (t & 1) * 4608 + (w * 16 + l15) * 72;
      us4 k0, k1;
      k0.x = f2bf(p0[0]); k0.y = f2bf(p0[1]); k0.z = f2bf(p0[2]); k0.w = f2bf(p0[3]);
      k1.x = f2bf(p1[0]); k1.y = f2bf(p1[1]); k1.z = f2bf(p1[2]); k1.w = f2bf(p1[3]);
      *(unsigned long long*)(prow + lq * 8)      = __builtin_bit_cast(unsigned long long, k0);
      *(unsigned long long*)(prow + 32 + lq * 8) = __builtin_bit_cast(unsigned long long, k1);
      if (lq == 0) *(float*)(lds + AB + (t & 1) * 256 + (w * 16 + l15) * 4) = al;
      const bool anyn = __any(need);
      if (l == 0) *(int*)(lds + FL + (t & 1) * 16 + w * 4) = anyn ? 1 : 0;
      barrier_lgkm();
    }
    if (lq == 0) *(float*)(lds + LR + (w * 16 + l15) * 4) = l_;
    barrier_lgkm();                       // epilogue sync
  } else {
    // =================== PV-waves ===================
    const int pw = wid - 4;               // 0..7
    const int dbase = pw * 64;
    const int stid = pw * 64 + l;         // 0..511 for K staging

#define STAGEK(TT)                                                     \
    {                                                                  \
      const u16* ks = Kb + (size_t)(TT) * 16384;                       \
      char* kd = lds + ((TT) % 3) * 32768;                             \
      _Pragma("unroll") for (int i = 0; i < 4; ++i) {                  \
        const int cid = stid + i * 512;                                \
        const int ob = cid << 4;                                       \
        const int n_ = ob >> 10;                                       \
        const int cb = (ob & 1023) ^ ((n_ & 15) << 4);                 \
        gload16(ks + (size_t)n_ * 512 + (cb >> 1), kd + ob);           \
      }                                                                \
    }

    STAGEK(0)
    STAGEK(1)
    vmwait<4>();                          // K(0) landed; K(1) may fly
    barrier_lgkm();                       // #0
    f32x16 oA[2][2];
    const f32x16 z16 = {0.f,0.f,0.f,0.f, 0.f,0.f,0.f,0.f, 0.f,0.f,0.f,0.f, 0.f,0.f,0.f,0.f};
#pragma unroll
    for (int qt = 0; qt < 2; ++qt)
#pragma unroll
      for (int dt = 0; dt < 2; ++dt) oA[qt][dt] = z16;
    bf16x8 vrA[4], vrB[4];

#define PV_APPLY(PB_, VUSE)                                                      \
    {                                                                            \
      bf16x8 pa[2][2];                                                           \
      _Pragma("unroll") for (int qt = 0; qt < 2; ++qt)                           \
      _Pragma("unroll") for (int kh = 0; kh < 2; ++kh) {                         \
        const char* pr = lds + PB + (PB_) * 4608 + (qt * 32 + l31) * 72 +        \
                         kh * 32 + lh * 16;                                      \
        unsigned long long w2[2];                                                \
        w2[0] = *(const unsigned long long*)pr;                                  \
        w2[1] = *(const unsigned long long*)(pr + 8);                            \
        pa[qt][kh] = __builtin_bit_cast(bf16x8, w2);                             \
      }                                                                          \
      const int* flp = (const int*)(lds + FL + (PB_) * 16);                      \
      const int fl = flp[0] | flp[1] | flp[2] | flp[3];                          \
      if (fl) {                                                                  \
        _Pragma("unroll") for (int qt = 0; qt < 2; ++qt)                         \
        _Pragma("unroll") for (int rg = 0; rg < 16; ++rg) {                      \
          const int cr = (rg & 3) + 8 * (rg >> 2) + 4 * lh;                      \
          const float av = *(const float*)(lds + AB + (PB_) * 256 +              \
                                           (qt * 32 + cr) * 4);                  \
          oA[qt][0][rg] *= av; oA[qt][1][rg] *= av;                              \
        }                                                                        \
      }                                                                          \
      _Pragma("unroll") for (int qt = 0; qt < 2; ++qt)                           \
      _Pragma("unroll") for (int dt = 0; dt < 2; ++dt)                           \
      _Pragma("unroll") for (int kh = 0; kh < 2; ++kh)                           \
        oA[qt][dt] = __builtin_amdgcn_mfma_f32_32x32x16_bf16(pa[qt][kh],         \
                        VUSE[dt * 2 + kh], oA[qt][dt], 0, 0, 0);                 \
    }

#define PV_STEP(T, VUSE, VLOAD)                                                  \
    {                                                                            \
      const int t_ = (T);                                                        \
      if (t_ < 126) STAGEK(t_ + 2)                                               \
      vmwait<4>();                        /* V(t-1) + K(t+1) landed */           \
      if (t_ > 0) { PV_APPLY((t_ - 1) & 1, VUSE) }                               \
      {                                                                          \
        const u16* vsrc = Vb + (size_t)t_ * 16384;                               \
        _Pragma("unroll") for (int dt = 0; dt < 2; ++dt)                         \
        _Pragma("unroll") for (int kh = 0; kh < 2; ++kh) {                       \
          const int c4 = kh * 2 + lh;                                            \
          const int d = dbase + dt * 32 + l31;                                   \
          VLOAD[dt * 2 + kh] =                                                   \
              *(const bf16x8*)(vsrc + ((size_t)(c4 * 512 + (d ^ c4)) << 3));     \
        }                                                                        \
      }                                                                          \
      vmwait<8>();                        /* all older than K(t+2),V(t) */       \
      barrier_lgkm();                                                            \
    }

    for (int tt = 0; tt < 64; ++tt) {
      PV_STEP(2 * tt,     vrB, vrA)       // applies V(2tt-1) in vrB, loads V(2tt)->vrA
      PV_STEP(2 * tt + 1, vrA, vrB)
    }
    vmwait<0>();                          // V(127) in vrB
    PV_APPLY(1, vrB)                      // P(127), a(127)
    barrier_lgkm();                       // lrow published
#undef PV_STEP
#undef PV_APPLY
#undef STAGEK
    // epilogue: O /= l, store bf16
#pragma unroll
    for (int qt = 0; qt < 2; ++qt)
#pragma unroll
      for (int rg = 0; rg < 16; ++rg) {
        const int cr = (rg & 3) + 8 * (rg >> 2) + 4 * lh;
        const float li = 1.0f / *(const float*)(lds + LR + (qt * 32 + cr) * 4);
        u16* orow = Oo + ((size_t)(b * 4096 + qb * 64 + qt * 32 + cr)) * 512 + dbase + l31;
        orow[0]  = f2bf(oA[qt][0][rg] * li);
        orow[32] = f2bf(oA[qt][1][rg] * li);
      }
  }
}

extern "C" void kernel_launch(void* const* d_in, const int* in_sizes, int n_in,
                              void* d_out, int out_size, void* d_ws, size_t ws_size,
                              hipStream_t stream) {
  const float* x     = (const float*)d_in[0];
  const float* gamma = (const float*)d_in[1];
  const float* beta  = (const float*)d_in[2];
  const float* wq    = (const float*)d_in[3];
  const float* bq    = (const float*)d_in[4];
  const float* wk    = (const float*)d_in[5];
  const float* bk    = (const float*)d_in[6];
  const float* wv    = (const float*)d_in[7];
  const float* bv    = (const float*)d_in[8];
  const float* wo    = (const float*)d_in[9];
  const float* bo    = (const float*)d_in[10];
  float* out = (float*)d_out;

  char* ws = (char*)d_ws;
  const size_t SZ = (size_t)16384 * 512;
  u16* h    = (u16*)(ws);                 // 16 MB
  u16* q    = (u16*)(ws + SZ * 2);        // 16 MB (pre-scaled by C^-0.5)
  u16* k    = (u16*)(ws + SZ * 4);        // 16 MB
  u16* v8   = (u16*)(ws + SZ * 6);        // 16 MB, [B][N/8][C^(blk&3)][8]
  u16* aout = (u16*)(ws + SZ * 8);        // 16 MB
  u16* wT   = (u16*)(ws + SZ * 10);       // 4 x 512KB
  float* part  = (float*)(ws + SZ * 10 + 4 * 262144 * 2);
  float* stats = part + 2048;

  gn_partial<<<dim3(8, 32, 4), 256, 0, stream>>>(x, part);
  gn_finalize<<<1, 128, 0, stream>>>(part, stats);
  gn_apply<<<8192, 256, 0, stream>>>(x, gamma, beta, stats, h);

  wcast_t4<<<4096, 256, 0, stream>>>(wq, wk, wv, wo, wT);

  const float qs = 0.044194173824159216f;  // 512^-0.5
  gemm_qkv<<<dim3(128, 12), 256, 0, stream>>>(h, wT, bq, bk, bv, q, k, v8, qs);

  attn_kernel<<<256, 768, 0, stream>>>(q, k, v8, aout);

  gemm_oproj<<<dim3(128, 4), 256, 0, stream>>>(aout, wT + 3 * 262144, bo, x, out);
}